// Round 3
// baseline (497.548 us; speedup 1.0000x reference)
//
#include <hip/hip_runtime.h>

#define NN 100000
#define EE 500000
#define LDSW 136     // padded bf16 row stride in LDS
#define GEMM_NG 1563 // ceil(100000/16/4)

typedef __attribute__((ext_vector_type(8))) short v8s;
typedef __attribute__((ext_vector_type(4))) float v4f;

// ---------- bf16 helpers (RNE) ----------
__device__ __forceinline__ short f2b(float f) {
  unsigned u = __float_as_uint(f);
  unsigned r = (u + 0x7FFFu + ((u >> 16) & 1u)) >> 16;
  return (short)r;
}
__device__ __forceinline__ float b2f(short s) {
  return __uint_as_float(((unsigned)(unsigned short)s) << 16);
}

// ---------- zero fill ----------
__global__ __launch_bounds__(256) void zero_f4(float4* __restrict__ p, long n4) {
  long i = (long)blockIdx.x * 256 + threadIdx.x;
  if (i < n4) p[i] = make_float4(0.f, 0.f, 0.f, 0.f);
}

// ---------- CSR build (both edge types concatenated: [u2i | i2u]) ----------
// hist ALSO records each edge's rank within its dst segment (atomicAdd return
// value) -> CSR slot becomes deterministic (offs[dst]+rank), so the alpha
// kernels need NO atomics at all.
__global__ __launch_bounds__(256) void hist2_k(const int* __restrict__ ei_a,
                                               const int* __restrict__ ei_b,
                                               int* __restrict__ deg,
                                               int* __restrict__ rank) {
  int e = blockIdx.x * 256 + threadIdx.x;
  if (e < EE)
    rank[e] = atomicAdd(&deg[ei_a[EE + e]], 1);
  else if (e < 2 * EE)
    rank[e] = atomicAdd(&deg[NN + ei_b[e]], 1);  // ei_b[EE + (e-EE)]
}

__global__ __launch_bounds__(256) void scan1_k(const int* __restrict__ deg,
                                               int* __restrict__ offs,
                                               int* __restrict__ bsums, int n) {
  __shared__ int sd[256];
  int t = threadIdx.x;
  int idx = blockIdx.x * 1024 + t * 4;
  int v0 = (idx < n) ? deg[idx] : 0;
  int v1 = (idx + 1 < n) ? deg[idx + 1] : 0;
  int v2 = (idx + 2 < n) ? deg[idx + 2] : 0;
  int v3 = (idx + 3 < n) ? deg[idx + 3] : 0;
  int s = v0 + v1 + v2 + v3;
  sd[t] = s;
  __syncthreads();
  for (int off = 1; off < 256; off <<= 1) {
    int x = (t >= off) ? sd[t - off] : 0;
    __syncthreads();
    sd[t] += x;
    __syncthreads();
  }
  int excl = sd[t] - s;
  if (idx < n) offs[idx] = excl;
  if (idx + 1 < n) offs[idx + 1] = excl + v0;
  if (idx + 2 < n) offs[idx + 2] = excl + v0 + v1;
  if (idx + 3 < n) offs[idx + 3] = excl + v0 + v1 + v2;
  if (t == 255) bsums[blockIdx.x] = sd[255];
}

__global__ __launch_bounds__(256) void scan2_k(int* __restrict__ bsums, int G,
                                               int* __restrict__ offs_last) {
  __shared__ int sd[256];
  int t = threadIdx.x;
  int v = (t < G) ? bsums[t] : 0;
  sd[t] = v;
  __syncthreads();
  for (int off = 1; off < 256; off <<= 1) {
    int x = (t >= off) ? sd[t - off] : 0;
    __syncthreads();
    sd[t] += x;
    __syncthreads();
  }
  int incl = sd[t];
  if (t < G) bsums[t] = incl - v;
  if (t == G - 1) *offs_last = incl;
}

__global__ __launch_bounds__(256) void scan3_k(int* __restrict__ offs,
                                               const int* __restrict__ bsums,
                                               int n) {
  int base = bsums[blockIdx.x];
  int idx = blockIdx.x * 1024 + threadIdx.x * 4;
#pragma unroll
  for (int i = 0; i < 4; ++i) {
    int id = idx + i;
    if (id < n) offs[id] += base;
  }
}

// ---------- prep for all 3 convs: Wt bf16 transposes + [Was|Wda] folds + Wea + WdaL1 ----------
// conv c in {0,1,2} -> param slice pi {0,1,3}. foldB[c] cols 0-3 = Was(own),
// cols 4-7 = Wda of the conv whose dst-features equal this conv's A matrix.
__global__ __launch_bounds__(256) void prep_k(
    const float* __restrict__ W_src, const float* __restrict__ W_dst,
    const float* __restrict__ W_edge, const float* __restrict__ att_src,
    const float* __restrict__ att_dst, const float* __restrict__ att_edge,
    short* __restrict__ Wt, short* __restrict__ foldB, float* __restrict__ Wea,
    float* __restrict__ WdaL1) {
  int b = blockIdx.x, t = threadIdx.x;
  if (b < 192) {
    int c = b >> 6, bb = b & 63;
    int pi = (c == 2) ? 3 : c;
    const float* W = W_src + pi * 16384;
    int idx = bb * 256 + t;
    int k = idx >> 7, n = idx & 127;
    Wt[c * 16384 + n * 128 + k] = f2b(W[idx]);
    return;
  }
  int c = b - 192;
  int pi = (c == 2) ? 3 : c;
  int wd_pi = (c == 0) ? 1 : ((c == 1) ? 0 : 3);
  const float* W = W_src + pi * 16384;
  const float* as_ = att_src + pi * 128;
  const float* Wd = W_dst + wd_pi * 16384;
  const float* ad_ = att_dst + wd_pi * 128;
  const float* We = W_edge + pi * 2048;
  const float* ae_ = att_edge + pi * 128;
  short* fB = foldB + c * 2048;
  float* WeaC = Wea + c * 64;
  if (t < 128) {
#pragma unroll
    for (int h = 0; h < 4; ++h) {
      float s = 0.f;
      for (int cc = 0; cc < 32; ++cc)
        s += W[t * 128 + h * 32 + cc] * as_[h * 32 + cc];
      fB[t * 16 + h] = f2b(s);
    }
#pragma unroll
    for (int j = 8; j < 16; ++j) fB[t * 16 + j] = 0;
  } else {
    int k = t - 128;
    float o[4];
#pragma unroll
    for (int h = 0; h < 4; ++h) {
      float s = 0.f;
      for (int cc = 0; cc < 32; ++cc)
        s += Wd[k * 128 + h * 32 + cc] * ad_[h * 32 + cc];
      o[h] = s;
      fB[k * 16 + 4 + h] = f2b(s);
    }
    if (c == 2) ((float4*)WdaL1)[k] = make_float4(o[0], o[1], o[2], o[3]);
    if (k < 16) {
      float wv[4];
#pragma unroll
      for (int h = 0; h < 4; ++h) {
        float s = 0.f;
        for (int cc = 0; cc < 32; ++cc)
          s += We[k * 128 + h * 32 + cc] * ae_[h * 32 + cc];
        wv[h] = s;
      }
      ((float4*)WeaC)[k] = make_float4(wv[0], wv[1], wv[2], wv[3]);
    }
  }
}

// ---------- GEMM body: hs=A@W (bf16), es=A@Was, ed=A@Wda ----------
template <bool A_F32, bool STORE_ED>
__device__ __forceinline__ void gemm_body(int blk, const void* __restrict__ Ap,
                                          const short* __restrict__ Wt,
                                          const short* __restrict__ foldB16,
                                          short* __restrict__ hs,
                                          float* __restrict__ es,
                                          float* __restrict__ ed, int N,
                                          short* sW, short* sF, short* sC) {
  int t = threadIdx.x;
  {
    const int4* wp = (const int4*)Wt;
    for (int c = t; c < 2048; c += 256) {
      int row = c >> 4, col = c & 15;
      *(int4*)&sW[row * LDSW + col * 8] = wp[c];
    }
    ((int4*)sF)[t] = ((const int4*)foldB16)[t];
  }
  __syncthreads();
  int wid = t >> 6, lane = t & 63;
  long tile = (long)blk * 4 + wid;
  if (tile * 16 >= N) return;
  long row0 = tile * 16;
  int m = lane & 15, q = lane >> 4;
  v8s af[4];
  if (A_F32) {
    const float* arow = (const float*)Ap + (row0 + m) * 128 + q * 8;
#pragma unroll
    for (int kc = 0; kc < 4; ++kc) {
      float4 lo = *(const float4*)(arow + kc * 32);
      float4 hi = *(const float4*)(arow + kc * 32 + 4);
      v8s f;
      f[0] = f2b(lo.x); f[1] = f2b(lo.y); f[2] = f2b(lo.z); f[3] = f2b(lo.w);
      f[4] = f2b(hi.x); f[5] = f2b(hi.y); f[6] = f2b(hi.z); f[7] = f2b(hi.w);
      af[kc] = f;
    }
  } else {
    const short* arow = (const short*)Ap + (row0 + m) * 128 + q * 8;
#pragma unroll
    for (int kc = 0; kc < 4; ++kc) af[kc] = *(const v8s*)(arow + kc * 32);
  }
  v8s ff[4];
#pragma unroll
  for (int kc = 0; kc < 4; ++kc) {
    v8s f;
#pragma unroll
    for (int j = 0; j < 8; ++j) f[j] = sF[(kc * 32 + q * 8 + j) * 16 + m];
    ff[kc] = f;
  }
  v4f zero4 = {0.f, 0.f, 0.f, 0.f};
  v4f accf = zero4;
#pragma unroll
  for (int kc = 0; kc < 4; ++kc)
    accf = __builtin_amdgcn_mfma_f32_16x16x32_bf16(af[kc], ff[kc], accf, 0, 0, 0);
  v4f acc[8];
#pragma unroll
  for (int ct = 0; ct < 8; ++ct) {
    acc[ct] = zero4;
#pragma unroll
    for (int kc = 0; kc < 4; ++kc) {
      v8s bfr = *(const v8s*)&sW[(ct * 16 + m) * LDSW + kc * 32 + q * 8];
      acc[ct] =
          __builtin_amdgcn_mfma_f32_16x16x32_bf16(af[kc], bfr, acc[ct], 0, 0, 0);
    }
  }
#pragma unroll
  for (int r = 0; r < 4; ++r) {
    long row = row0 + q * 4 + r;
    if (m < 4)
      es[row * 4 + m] = accf[r];
    else if (STORE_ED && m < 8)
      ed[row * 4 + (m - 4)] = accf[r];
  }
  short* myC = sC + wid * 16 * LDSW;
#pragma unroll
  for (int ct = 0; ct < 8; ++ct)
#pragma unroll
    for (int r = 0; r < 4; ++r)
      myC[(q * 4 + r) * LDSW + ct * 16 + m] = f2b(acc[ct][r]);
  {
    int row = lane >> 2, part = lane & 3;
    short* dst = hs + (row0 + row) * 128 + part * 32;
#pragma unroll
    for (int i = 0; i < 4; ++i)
      *(int4*)(dst + i * 8) = *(int4*)&myC[row * LDSW + part * 32 + i * 8];
  }
}

// layer-0: both convs in one launch (block halves)
__global__ __launch_bounds__(256) void gemm01_k(
    const float* __restrict__ xu, const float* __restrict__ xi,
    const short* __restrict__ Wt, const short* __restrict__ foldB,
    short* __restrict__ hsU, short* __restrict__ hsI, float* __restrict__ esU,
    float* __restrict__ esI, float* __restrict__ edC0,
    float* __restrict__ edC1) {
  __shared__ short sW[128 * LDSW];
  __shared__ short sF[128 * 16];
  __shared__ short sC[4 * 16 * LDSW];
  int half = blockIdx.x >= GEMM_NG;
  int blk = blockIdx.x - (half ? GEMM_NG : 0);
  gemm_body<true, true>(blk, half ? (const void*)xi : (const void*)xu,
                        Wt + half * 16384, foldB + half * 2048,
                        half ? hsI : hsU, half ? esI : esU,
                        half ? edC0 : edC1, NN, sW, sF, sC);
}

__global__ __launch_bounds__(256) void gemm2_k(const short* __restrict__ A,
                                               const short* __restrict__ Wt,
                                               const short* __restrict__ foldB,
                                               short* __restrict__ hs,
                                               float* __restrict__ es) {
  __shared__ short sW[128 * LDSW];
  __shared__ short sF[128 * 16];
  __shared__ short sC[4 * 16 * LDSW];
  gemm_body<false, false>(blockIdx.x, A, Wt + 2 * 16384, foldB + 2 * 2048, hs,
                          es, nullptr, NN, sW, sF, sC);
}

// ---------- alpha: w4 = exp(leaky_relu(es[src]+ed[dst]+ea@Wea)) ----------
__device__ __forceinline__ float4 alpha_w(int s, int d,
                                          const float* __restrict__ ea_e,
                                          const float* __restrict__ es,
                                          const float* __restrict__ ed,
                                          const float* __restrict__ WeaC) {
  float4 es4 = ((const float4*)es)[s];
  float4 ed4 = ((const float4*)ed)[d];
  float acc[4] = {es4.x + ed4.x, es4.y + ed4.y, es4.z + ed4.z, es4.w + ed4.w};
  const float4* ea4 = (const float4*)ea_e;
#pragma unroll
  for (int qq = 0; qq < 4; ++qq) {
    float4 a = ea4[qq];
    float av[4] = {a.x, a.y, a.z, a.w};
#pragma unroll
    for (int i = 0; i < 4; ++i) {
      float4 w = ((const float4*)WeaC)[qq * 4 + i];
      acc[0] += av[i] * w.x;
      acc[1] += av[i] * w.y;
      acc[2] += av[i] * w.z;
      acc[3] += av[i] * w.w;
    }
  }
  float4 r;
#pragma unroll
  for (int h = 0; h < 4; ++h) {
    float v = acc[h];
    v = (v >= 0.f) ? v : 0.2f * v;
    ((float*)&r)[h] = __expf(v);  // alphas O(1): safe without max-subtraction
  }
  return r;
}

// slot = offs[dst] + rank[e]: deterministic, NO atomics. Scatter stores are
// nontemporal (no L2 allocate -> no RMW fetch, no line write-amplification).
__global__ __launch_bounds__(256) void alpha01_k(
    const int* __restrict__ ei_a, const int* __restrict__ ei_b,
    const int* __restrict__ rank2, const int* __restrict__ offs2,
    const float* __restrict__ ea_a, const float* __restrict__ ea_b,
    const float* __restrict__ esU, const float* __restrict__ esI,
    const float* __restrict__ edC0, const float* __restrict__ edC1,
    const float* __restrict__ Wea, float* __restrict__ wbufF,
    int* __restrict__ ss2) {
  int e = blockIdx.x * 256 + threadIdx.x;
  if (e >= 2 * EE) return;
  bool h0 = e < EE;
  int el = h0 ? e : e - EE;
  const int* ei = h0 ? ei_a : ei_b;
  const float* ea = h0 ? ea_a : ea_b;
  const float* es = h0 ? esU : esI;
  const float* ed = h0 ? edC0 : edC1;
  const float* WeaC = Wea + (h0 ? 0 : 64);
  int s = ei[el], d = ei[EE + el];
  int dp = h0 ? d : NN + d;
  int k = offs2[dp] + rank2[e];
  float4 w4 = alpha_w(s, d, ea + (long)el * 16, es, ed, WeaC);
  v4f wv = {w4.x, w4.y, w4.z, w4.w};
  __builtin_nontemporal_store(wv, (v4f*)(wbufF + (long)k * 4));
  __builtin_nontemporal_store(s, ss2 + k);
}

// layer-1 slots/sources are IDENTICAL to layer-0's user-dst half (same edges,
// deterministic slots) -> only w needs rewriting, ss2 is reused as-is.
__global__ __launch_bounds__(256) void alpha2_k(
    const int* __restrict__ ei_b, const int* __restrict__ rank2,
    const int* __restrict__ offs2, const float* __restrict__ ea_b,
    const float* __restrict__ es2, const float* __restrict__ edL1,
    const float* __restrict__ Wea, float* __restrict__ wbufF) {
  int e = blockIdx.x * 256 + threadIdx.x;
  if (e >= EE) return;
  int s = ei_b[e], d = ei_b[EE + e];
  int k = offs2[NN + d] + rank2[EE + e];
  float4 w4 = alpha_w(s, d, ea_b + (long)e * 16, es2, edL1, Wea + 128);
  v4f wv = {w4.x, w4.y, w4.z, w4.w};
  __builtin_nontemporal_store(wv, (v4f*)(wbufF + (long)k * 4));
}

// ---------- gather: weighted sum + bias + LN + ReLU ----------
// 16 lanes per dst node; lane j owns channels 8j..8j+7 (int4 = 8 bf16 per
// load); head h=j>>2; 4 nodes per wave. 2-edge unroll with dual accumulator
// banks.
__device__ __forceinline__ void fma8(float* a, float w, int4 p) {
  const unsigned m = 0xFFFF0000u;
  a[0] += w * __uint_as_float(((unsigned)p.x) << 16);
  a[1] += w * __uint_as_float(((unsigned)p.x) & m);
  a[2] += w * __uint_as_float(((unsigned)p.y) << 16);
  a[3] += w * __uint_as_float(((unsigned)p.y) & m);
  a[4] += w * __uint_as_float(((unsigned)p.z) << 16);
  a[5] += w * __uint_as_float(((unsigned)p.z) & m);
  a[6] += w * __uint_as_float(((unsigned)p.w) << 16);
  a[7] += w * __uint_as_float(((unsigned)p.w) & m);
}

__device__ __forceinline__ void gather_body16(
    int rs, int re, int j, int h, const int* __restrict__ ss,
    const short* __restrict__ hs, const float* __restrict__ wbufF,
    const float* __restrict__ bias, const float* __restrict__ gamma,
    const float* __restrict__ beta, float* y) {
  float den0 = 0.f, den1 = 0.f;
  float a[8] = {0.f, 0.f, 0.f, 0.f, 0.f, 0.f, 0.f, 0.f};
  float b[8] = {0.f, 0.f, 0.f, 0.f, 0.f, 0.f, 0.f, 0.f};
  int k = rs;
  for (; k + 1 < re; k += 2) {
    int s0 = ss[k], s1 = ss[k + 1];
    float w0 = wbufF[(long)k * 4 + h];
    float w1 = wbufF[(long)(k + 1) * 4 + h];
    int4 p0 = *(const int4*)(hs + (long)s0 * 128 + j * 8);
    int4 p1 = *(const int4*)(hs + (long)s1 * 128 + j * 8);
    den0 += w0;
    den1 += w1;
    fma8(a, w0, p0);
    fma8(b, w1, p1);
  }
  if (k < re) {
    int s0 = ss[k];
    float w0 = wbufF[(long)k * 4 + h];
    int4 p0 = *(const int4*)(hs + (long)s0 * 128 + j * 8);
    den0 += w0;
    fma8(a, w0, p0);
  }
  float inv = 1.f / (den0 + den1 + 1e-16f);
  float4 b4a = ((const float4*)bias)[j * 2];
  float4 b4b = ((const float4*)bias)[j * 2 + 1];
  float o[8];
  o[0] = (a[0] + b[0]) * inv + b4a.x;
  o[1] = (a[1] + b[1]) * inv + b4a.y;
  o[2] = (a[2] + b[2]) * inv + b4a.z;
  o[3] = (a[3] + b[3]) * inv + b4a.w;
  o[4] = (a[4] + b[4]) * inv + b4b.x;
  o[5] = (a[5] + b[5]) * inv + b4b.y;
  o[6] = (a[6] + b[6]) * inv + b4b.z;
  o[7] = (a[7] + b[7]) * inv + b4b.w;
  float s1 = 0.f, s2 = 0.f;
#pragma unroll
  for (int i = 0; i < 8; ++i) {
    s1 += o[i];
    s2 += o[i] * o[i];
  }
#pragma unroll
  for (int mm = 1; mm <= 8; mm <<= 1) {
    s1 += __shfl_xor(s1, mm);
    s2 += __shfl_xor(s2, mm);
  }
  float mu = s1 * (1.f / 128.f);
  float var = s2 * (1.f / 128.f) - mu * mu;
  float rstd = rsqrtf(var + 1e-5f);
  float4 g4a = ((const float4*)gamma)[j * 2];
  float4 g4b = ((const float4*)gamma)[j * 2 + 1];
  float4 e4a = ((const float4*)beta)[j * 2];
  float4 e4b = ((const float4*)beta)[j * 2 + 1];
  y[0] = fmaxf((o[0] - mu) * rstd * g4a.x + e4a.x, 0.f);
  y[1] = fmaxf((o[1] - mu) * rstd * g4a.y + e4a.y, 0.f);
  y[2] = fmaxf((o[2] - mu) * rstd * g4a.z + e4a.z, 0.f);
  y[3] = fmaxf((o[3] - mu) * rstd * g4a.w + e4a.w, 0.f);
  y[4] = fmaxf((o[4] - mu) * rstd * g4b.x + e4b.x, 0.f);
  y[5] = fmaxf((o[5] - mu) * rstd * g4b.y + e4b.y, 0.f);
  y[6] = fmaxf((o[6] - mu) * rstd * g4b.z + e4b.z, 0.f);
  y[7] = fmaxf((o[7] - mu) * rstd * g4b.w + e4b.w, 0.f);
}

// layer-0 both convs: g<NN item (conv0) -> bufXI; g>=NN user (conv1) -> bufXU + edL1 fuse
__global__ __launch_bounds__(256) void gather01_k(
    const int* __restrict__ offs2, const int* __restrict__ ss2,
    const short* __restrict__ hsU, const short* __restrict__ hsI,
    const float* __restrict__ wbufF, const float* __restrict__ bias,
    const float* __restrict__ ln_g, const float* __restrict__ ln_b,
    short* __restrict__ bufXI, short* __restrict__ bufXU,
    const float* __restrict__ WdaL1, float* __restrict__ edL1) {
  int t = threadIdx.x;
  int j = t & 15, h = j >> 2;
  int g = blockIdx.x * 16 + (t >> 4);
  if (g >= 2 * NN) return;
  bool item = g < NN;  // NN % 16 == 0 -> uniform per block
  const short* hs = item ? hsU : hsI;
  const float* bi = bias + (item ? 0 : 128);
  const float* ga = ln_g + (item ? 128 : 0);
  const float* be = ln_b + (item ? 128 : 0);
  float y[8];
  gather_body16(offs2[g], offs2[g + 1], j, h, ss2, hs, wbufF, bi, ga, be, y);
  long n = item ? g : g - NN;
  int4 pk;
  pk.x = (int)((unsigned)(unsigned short)f2b(y[0]) |
               ((unsigned)(unsigned short)f2b(y[1]) << 16));
  pk.y = (int)((unsigned)(unsigned short)f2b(y[2]) |
               ((unsigned)(unsigned short)f2b(y[3]) << 16));
  pk.z = (int)((unsigned)(unsigned short)f2b(y[4]) |
               ((unsigned)(unsigned short)f2b(y[5]) << 16));
  pk.w = (int)((unsigned)(unsigned short)f2b(y[6]) |
               ((unsigned)(unsigned short)f2b(y[7]) << 16));
  *(int4*)((item ? bufXI : bufXU) + n * 128 + j * 8) = pk;
  if (!item) {  // fold next layer's ed = y @ WdaL1
    float e0 = 0.f, e1 = 0.f, e2 = 0.f, e3 = 0.f;
#pragma unroll
    for (int r = 0; r < 8; ++r) {
      float4 wr = ((const float4*)WdaL1)[j * 8 + r];
      e0 += y[r] * wr.x;
      e1 += y[r] * wr.y;
      e2 += y[r] * wr.z;
      e3 += y[r] * wr.w;
    }
#pragma unroll
    for (int mm = 1; mm <= 8; mm <<= 1) {
      e0 += __shfl_xor(e0, mm);
      e1 += __shfl_xor(e1, mm);
      e2 += __shfl_xor(e2, mm);
      e3 += __shfl_xor(e3, mm);
    }
    if (j == 0) ((float4*)edL1)[n] = make_float4(e0, e1, e2, e3);
  }
}

__global__ __launch_bounds__(256) void gather2_k(
    const int* __restrict__ offs, const int* __restrict__ ss2,
    const short* __restrict__ hs2, const float* __restrict__ wbufF,
    const float* __restrict__ bias, const float* __restrict__ ln_g,
    const float* __restrict__ ln_b, float* __restrict__ out) {
  int t = threadIdx.x;
  int j = t & 15, h = j >> 2;
  int n = blockIdx.x * 16 + (t >> 4);
  if (n >= NN) return;
  float y[8];
  gather_body16(offs[n], offs[n + 1], j, h, ss2, hs2, wbufF, bias, ln_g, ln_b,
                y);
  ((float4*)out)[(long)n * 32 + j * 2] = make_float4(y[0], y[1], y[2], y[3]);
  ((float4*)out)[(long)n * 32 + j * 2 + 1] =
      make_float4(y[4], y[5], y[6], y[7]);
}

extern "C" void kernel_launch(void* const* d_in, const int* in_sizes, int n_in,
                              void* d_out, int out_size, void* d_ws,
                              size_t ws_size, hipStream_t stream) {
  const float* x_user = (const float*)d_in[0];
  const float* x_item = (const float*)d_in[1];
  const int* ei_u2i = (const int*)d_in[2];
  const int* ei_i2u = (const int*)d_in[3];
  const float* ea_u2i = (const float*)d_in[4];
  const float* ea_i2u = (const float*)d_in[5];
  const float* W_src = (const float*)d_in[6];
  const float* W_dst = (const float*)d_in[7];
  const float* W_edge = (const float*)d_in[8];
  const float* att_src = (const float*)d_in[9];
  const float* att_dst = (const float*)d_in[10];
  const float* att_edge = (const float*)d_in[11];
  const float* bias = (const float*)d_in[12];
  const float* ln_g = (const float*)d_in[13];
  const float* ln_b = (const float*)d_in[14];

  char* w = (char*)d_ws;
  auto alloc = [&](size_t bytes) {
    void* p = w;
    w += (bytes + 255) & ~(size_t)255;
    return p;
  };
  const size_t NBH = (size_t)NN * 128 * sizeof(short);
  short* hsU = (short*)alloc(NBH);
  short* hsI = (short*)alloc(NBH);
  short* hs2 = (short*)alloc(NBH);
  short* bufXI = (short*)alloc(NBH);
  short* bufXU = (short*)alloc(NBH);
  float* esU = (float*)alloc((size_t)NN * 4 * sizeof(float));
  float* esI = (float*)alloc((size_t)NN * 4 * sizeof(float));
  float* es2 = (float*)alloc((size_t)NN * 4 * sizeof(float));
  float* edC0 = (float*)alloc((size_t)NN * 4 * sizeof(float));
  float* edC1 = (float*)alloc((size_t)NN * 4 * sizeof(float));
  float* edL1 = (float*)alloc((size_t)NN * 4 * sizeof(float));
  float* wbufF = (float*)alloc((size_t)2 * EE * 4 * sizeof(float));  // 16MB
  short* Wt = (short*)alloc(3 * 16384 * sizeof(short));
  short* foldB = (short*)alloc(3 * 2048 * sizeof(short));
  float* Wea = (float*)alloc(3 * 64 * sizeof(float));
  float* WdaL1 = (float*)alloc(128 * 4 * sizeof(float));
  int* deg2 = (int*)alloc((size_t)2 * NN * sizeof(int));
  int* bsums = (int*)alloc(1024);
  int* offs2 = (int*)alloc((size_t)(2 * NN + 8) * sizeof(int));
  int* ss2 = (int*)alloc((size_t)2 * EE * sizeof(int));
  int* rank2 = (int*)alloc((size_t)2 * EE * sizeof(int));

  const int E2G = (2 * EE + 255) / 256;            // 3907
  const int SCAN_G2 = (2 * NN + 1023) / 1024;      // 196

  // ---- CSR (both edge types, concatenated) : 5 launches ----
  zero_f4<<<(2 * NN / 4 + 255) / 256, 256, 0, stream>>>((float4*)deg2,
                                                        2 * NN / 4);
  hist2_k<<<E2G, 256, 0, stream>>>(ei_u2i, ei_i2u, deg2, rank2);
  scan1_k<<<SCAN_G2, 256, 0, stream>>>(deg2, offs2, bsums, 2 * NN);
  scan2_k<<<1, 256, 0, stream>>>(bsums, SCAN_G2, offs2 + 2 * NN);
  scan3_k<<<SCAN_G2, 256, 0, stream>>>(offs2, bsums, 2 * NN);

  // ---- params + layer 0 : 4 launches ----
  prep_k<<<195, 256, 0, stream>>>(W_src, W_dst, W_edge, att_src, att_dst,
                                  att_edge, Wt, foldB, Wea, WdaL1);
  gemm01_k<<<2 * GEMM_NG, 256, 0, stream>>>(x_user, x_item, Wt, foldB, hsU,
                                            hsI, esU, esI, edC0, edC1);
  alpha01_k<<<E2G, 256, 0, stream>>>(ei_u2i, ei_i2u, rank2, offs2, ea_u2i,
                                     ea_i2u, esU, esI, edC0, edC1, Wea, wbufF,
                                     ss2);
  gather01_k<<<2 * NN / 16, 256, 0, stream>>>(offs2, ss2, hsU, hsI, wbufF,
                                              bias, ln_g, ln_b, bufXI, bufXU,
                                              WdaL1, edL1);

  // ---- layer 1 (user path only; item path dead) : 3 launches ----
  gemm2_k<<<GEMM_NG, 256, 0, stream>>>(bufXI, Wt, foldB, hs2, es2);
  alpha2_k<<<(EE + 255) / 256, 256, 0, stream>>>(ei_i2u, rank2, offs2, ea_i2u,
                                                 es2, edL1, Wea, wbufF);
  gather2_k<<<NN / 16, 256, 0, stream>>>(offs2 + NN, ss2, hs2, wbufF,
                                         bias + 3 * 128, ln_g + 2 * 128,
                                         ln_b + 2 * 128, (float*)d_out);
}

// Round 4
// 455.174 us; speedup vs baseline: 1.0931x; 1.0931x over previous
//
#include <hip/hip_runtime.h>

#define NN 100000
#define EE 500000
#define LDSW 136     // padded bf16 row stride in LDS
#define GEMM_NG 1563 // ceil(100000/16/4)
#define EAW_G 1954   // ceil(EE/256)

typedef __attribute__((ext_vector_type(8))) short v8s;
typedef __attribute__((ext_vector_type(4))) float v4f;

// ---------- bf16 helpers (RNE) ----------
__device__ __forceinline__ short f2b(float f) {
  unsigned u = __float_as_uint(f);
  unsigned r = (u + 0x7FFFu + ((u >> 16) & 1u)) >> 16;
  return (short)r;
}

// ---------- zero fill ----------
__global__ __launch_bounds__(256) void zero_f4(float4* __restrict__ p, long n4) {
  long i = (long)blockIdx.x * 256 + threadIdx.x;
  if (i < n4) p[i] = make_float4(0.f, 0.f, 0.f, 0.f);
}

// ---------- CSR build (both edge types concatenated: [u2i | i2u]) ----------
// hist records each edge's rank within its dst segment (atomicAdd return
// value) -> CSR slot is deterministic (offs[dst]+rank), no later atomics.
__global__ __launch_bounds__(256) void hist2_k(const int* __restrict__ ei_a,
                                               const int* __restrict__ ei_b,
                                               int* __restrict__ deg,
                                               int* __restrict__ rank) {
  int e = blockIdx.x * 256 + threadIdx.x;
  if (e < EE)
    rank[e] = atomicAdd(&deg[ei_a[EE + e]], 1);
  else if (e < 2 * EE)
    rank[e] = atomicAdd(&deg[NN + ei_b[e]], 1);  // ei_b[EE + (e-EE)]
}

__global__ __launch_bounds__(256) void scan1_k(const int* __restrict__ deg,
                                               int* __restrict__ offs,
                                               int* __restrict__ bsums, int n) {
  __shared__ int sd[256];
  int t = threadIdx.x;
  int idx = blockIdx.x * 1024 + t * 4;
  int v0 = (idx < n) ? deg[idx] : 0;
  int v1 = (idx + 1 < n) ? deg[idx + 1] : 0;
  int v2 = (idx + 2 < n) ? deg[idx + 2] : 0;
  int v3 = (idx + 3 < n) ? deg[idx + 3] : 0;
  int s = v0 + v1 + v2 + v3;
  sd[t] = s;
  __syncthreads();
  for (int off = 1; off < 256; off <<= 1) {
    int x = (t >= off) ? sd[t - off] : 0;
    __syncthreads();
    sd[t] += x;
    __syncthreads();
  }
  int excl = sd[t] - s;
  if (idx < n) offs[idx] = excl;
  if (idx + 1 < n) offs[idx + 1] = excl + v0;
  if (idx + 2 < n) offs[idx + 2] = excl + v0 + v1;
  if (idx + 3 < n) offs[idx + 3] = excl + v0 + v1 + v2;
  if (t == 255) bsums[blockIdx.x] = sd[255];
}

__global__ __launch_bounds__(256) void scan2_k(int* __restrict__ bsums, int G,
                                               int* __restrict__ offs_last) {
  __shared__ int sd[256];
  int t = threadIdx.x;
  int v = (t < G) ? bsums[t] : 0;
  sd[t] = v;
  __syncthreads();
  for (int off = 1; off < 256; off <<= 1) {
    int x = (t >= off) ? sd[t - off] : 0;
    __syncthreads();
    sd[t] += x;
    __syncthreads();
  }
  int incl = sd[t];
  if (t < G) bsums[t] = incl - v;
  if (t == G - 1) *offs_last = incl;
}

__global__ __launch_bounds__(256) void scan3_k(int* __restrict__ offs,
                                               const int* __restrict__ bsums,
                                               int n) {
  int base = bsums[blockIdx.x];
  int idx = blockIdx.x * 1024 + threadIdx.x * 4;
#pragma unroll
  for (int i = 0; i < 4; ++i) {
    int id = idx + i;
    if (id < n) offs[id] += base;
  }
}

// lean CSR scatter: ONE 8B record {src, edge_id} per edge, deterministic slot,
// no atomics (fire-and-forget stores). Serves BOTH layers (same slots/edges).
__global__ __launch_bounds__(256) void scatter_k(const int* __restrict__ ei_a,
                                                 const int* __restrict__ ei_b,
                                                 const int* __restrict__ rank2,
                                                 const int* __restrict__ offs2,
                                                 int2* __restrict__ prs) {
  int e = blockIdx.x * 256 + threadIdx.x;
  if (e >= 2 * EE) return;
  int s, dp, el;
  if (e < EE) {
    el = e;
    s = ei_a[e];
    dp = ei_a[EE + e];
  } else {
    el = e - EE;
    s = ei_b[el];
    dp = NN + ei_b[e];
  }
  int k = offs2[dp] + rank2[e];
  prs[k] = make_int2(s, el);
}

// ---------- prep for all 3 convs: Wt bf16 transposes + [Was|Wda] folds + Wea + WdaL1 ----------
__global__ __launch_bounds__(256) void prep_k(
    const float* __restrict__ W_src, const float* __restrict__ W_dst,
    const float* __restrict__ W_edge, const float* __restrict__ att_src,
    const float* __restrict__ att_dst, const float* __restrict__ att_edge,
    short* __restrict__ Wt, short* __restrict__ foldB, float* __restrict__ Wea,
    float* __restrict__ WdaL1) {
  int b = blockIdx.x, t = threadIdx.x;
  if (b < 192) {
    int c = b >> 6, bb = b & 63;
    int pi = (c == 2) ? 3 : c;
    const float* W = W_src + pi * 16384;
    int idx = bb * 256 + t;
    int k = idx >> 7, n = idx & 127;
    Wt[c * 16384 + n * 128 + k] = f2b(W[idx]);
    return;
  }
  int c = b - 192;
  int pi = (c == 2) ? 3 : c;
  int wd_pi = (c == 0) ? 1 : ((c == 1) ? 0 : 3);
  const float* W = W_src + pi * 16384;
  const float* as_ = att_src + pi * 128;
  const float* Wd = W_dst + wd_pi * 16384;
  const float* ad_ = att_dst + wd_pi * 128;
  const float* We = W_edge + pi * 2048;
  const float* ae_ = att_edge + pi * 128;
  short* fB = foldB + c * 2048;
  float* WeaC = Wea + c * 64;
  if (t < 128) {
#pragma unroll
    for (int h = 0; h < 4; ++h) {
      float s = 0.f;
      for (int cc = 0; cc < 32; ++cc)
        s += W[t * 128 + h * 32 + cc] * as_[h * 32 + cc];
      fB[t * 16 + h] = f2b(s);
    }
#pragma unroll
    for (int j = 8; j < 16; ++j) fB[t * 16 + j] = 0;
  } else {
    int k = t - 128;
    float o[4];
#pragma unroll
    for (int h = 0; h < 4; ++h) {
      float s = 0.f;
      for (int cc = 0; cc < 32; ++cc)
        s += Wd[k * 128 + h * 32 + cc] * ad_[h * 32 + cc];
      o[h] = s;
      fB[k * 16 + 4 + h] = f2b(s);
    }
    if (c == 2) ((float4*)WdaL1)[k] = make_float4(o[0], o[1], o[2], o[3]);
    if (k < 16) {
      float wv[4];
#pragma unroll
      for (int h = 0; h < 4; ++h) {
        float s = 0.f;
        for (int cc = 0; cc < 32; ++cc)
          s += We[k * 128 + h * 32 + cc] * ae_[h * 32 + cc];
        wv[h] = s;
      }
      ((float4*)WeaC)[k] = make_float4(wv[0], wv[1], wv[2], wv[3]);
    }
  }
}

// ---------- eaw: per-edge ea @ Wea, EDGE ORDER (fully coalesced, no scatter) ----------
__device__ __forceinline__ float4 dot16x4(const float4* __restrict__ ea4,
                                          const float* __restrict__ WeaC) {
  float acc[4] = {0.f, 0.f, 0.f, 0.f};
#pragma unroll
  for (int qq = 0; qq < 4; ++qq) {
    float4 a = ea4[qq];
    float av[4] = {a.x, a.y, a.z, a.w};
#pragma unroll
    for (int i = 0; i < 4; ++i) {
      float4 w = ((const float4*)WeaC)[qq * 4 + i];
      acc[0] += av[i] * w.x;
      acc[1] += av[i] * w.y;
      acc[2] += av[i] * w.z;
      acc[3] += av[i] * w.w;
    }
  }
  return make_float4(acc[0], acc[1], acc[2], acc[3]);
}

// blocks [0,EAW_G): eaw0 = ea_u2i @ Wea[0]
// blocks [EAW_G,2*EAW_G): eaw1 = ea_i2u @ Wea[1], eaw2 = ea_i2u @ Wea[2]
__global__ __launch_bounds__(256) void eaw_k(const float* __restrict__ ea_a,
                                             const float* __restrict__ ea_b,
                                             const float* __restrict__ Wea,
                                             float4* __restrict__ eaw0,
                                             float4* __restrict__ eaw1,
                                             float4* __restrict__ eaw2) {
  int half = blockIdx.x >= EAW_G;
  int e = (blockIdx.x - (half ? EAW_G : 0)) * 256 + threadIdx.x;
  if (e >= EE) return;
  const float4* ea4 = (const float4*)((half ? ea_b : ea_a) + (long)e * 16);
  float4 lo = ea4[0], l1 = ea4[1], l2 = ea4[2], l3 = ea4[3];
  float4 loc[4] = {lo, l1, l2, l3};
  if (!half) {
    eaw0[e] = dot16x4(loc, Wea);
  } else {
    eaw1[e] = dot16x4(loc, Wea + 64);
    eaw2[e] = dot16x4(loc, Wea + 128);
  }
}

// ---------- GEMM body: hs=A@W (bf16), es=A@Was, ed=A@Wda ----------
template <bool A_F32, bool STORE_ED>
__device__ __forceinline__ void gemm_body(int blk, const void* __restrict__ Ap,
                                          const short* __restrict__ Wt,
                                          const short* __restrict__ foldB16,
                                          short* __restrict__ hs,
                                          float* __restrict__ es,
                                          float* __restrict__ ed, int N,
                                          short* sW, short* sF, short* sC) {
  int t = threadIdx.x;
  {
    const int4* wp = (const int4*)Wt;
    for (int c = t; c < 2048; c += 256) {
      int row = c >> 4, col = c & 15;
      *(int4*)&sW[row * LDSW + col * 8] = wp[c];
    }
    ((int4*)sF)[t] = ((const int4*)foldB16)[t];
  }
  __syncthreads();
  int wid = t >> 6, lane = t & 63;
  long tile = (long)blk * 4 + wid;
  if (tile * 16 >= N) return;
  long row0 = tile * 16;
  int m = lane & 15, q = lane >> 4;
  v8s af[4];
  if (A_F32) {
    const float* arow = (const float*)Ap + (row0 + m) * 128 + q * 8;
#pragma unroll
    for (int kc = 0; kc < 4; ++kc) {
      float4 lo = *(const float4*)(arow + kc * 32);
      float4 hi = *(const float4*)(arow + kc * 32 + 4);
      v8s f;
      f[0] = f2b(lo.x); f[1] = f2b(lo.y); f[2] = f2b(lo.z); f[3] = f2b(lo.w);
      f[4] = f2b(hi.x); f[5] = f2b(hi.y); f[6] = f2b(hi.z); f[7] = f2b(hi.w);
      af[kc] = f;
    }
  } else {
    const short* arow = (const short*)Ap + (row0 + m) * 128 + q * 8;
#pragma unroll
    for (int kc = 0; kc < 4; ++kc) af[kc] = *(const v8s*)(arow + kc * 32);
  }
  v8s ff[4];
#pragma unroll
  for (int kc = 0; kc < 4; ++kc) {
    v8s f;
#pragma unroll
    for (int j = 0; j < 8; ++j) f[j] = sF[(kc * 32 + q * 8 + j) * 16 + m];
    ff[kc] = f;
  }
  v4f zero4 = {0.f, 0.f, 0.f, 0.f};
  v4f accf = zero4;
#pragma unroll
  for (int kc = 0; kc < 4; ++kc)
    accf = __builtin_amdgcn_mfma_f32_16x16x32_bf16(af[kc], ff[kc], accf, 0, 0, 0);
  v4f acc[8];
#pragma unroll
  for (int ct = 0; ct < 8; ++ct) {
    acc[ct] = zero4;
#pragma unroll
    for (int kc = 0; kc < 4; ++kc) {
      v8s bfr = *(const v8s*)&sW[(ct * 16 + m) * LDSW + kc * 32 + q * 8];
      acc[ct] =
          __builtin_amdgcn_mfma_f32_16x16x32_bf16(af[kc], bfr, acc[ct], 0, 0, 0);
    }
  }
#pragma unroll
  for (int r = 0; r < 4; ++r) {
    long row = row0 + q * 4 + r;
    if (m < 4)
      es[row * 4 + m] = accf[r];
    else if (STORE_ED && m < 8)
      ed[row * 4 + (m - 4)] = accf[r];
  }
  short* myC = sC + wid * 16 * LDSW;
#pragma unroll
  for (int ct = 0; ct < 8; ++ct)
#pragma unroll
    for (int r = 0; r < 4; ++r)
      myC[(q * 4 + r) * LDSW + ct * 16 + m] = f2b(acc[ct][r]);
  {
    int row = lane >> 2, part = lane & 3;
    short* dst = hs + (row0 + row) * 128 + part * 32;
#pragma unroll
    for (int i = 0; i < 4; ++i)
      *(int4*)(dst + i * 8) = *(int4*)&myC[row * LDSW + part * 32 + i * 8];
  }
}

// layer-0: both convs in one launch (block halves)
__global__ __launch_bounds__(256) void gemm01_k(
    const float* __restrict__ xu, const float* __restrict__ xi,
    const short* __restrict__ Wt, const short* __restrict__ foldB,
    short* __restrict__ hsU, short* __restrict__ hsI, float* __restrict__ esU,
    float* __restrict__ esI, float* __restrict__ edC0,
    float* __restrict__ edC1) {
  __shared__ short sW[128 * LDSW];
  __shared__ short sF[128 * 16];
  __shared__ short sC[4 * 16 * LDSW];
  int half = blockIdx.x >= GEMM_NG;
  int blk = blockIdx.x - (half ? GEMM_NG : 0);
  gemm_body<true, true>(blk, half ? (const void*)xi : (const void*)xu,
                        Wt + half * 16384, foldB + half * 2048,
                        half ? hsI : hsU, half ? esI : esU,
                        half ? edC0 : edC1, NN, sW, sF, sC);
}

__global__ __launch_bounds__(256) void gemm2_k(const short* __restrict__ A,
                                               const short* __restrict__ Wt,
                                               const short* __restrict__ foldB,
                                               short* __restrict__ hs,
                                               float* __restrict__ es) {
  __shared__ short sW[128 * LDSW];
  __shared__ short sF[128 * 16];
  __shared__ short sC[4 * 16 * LDSW];
  gemm_body<false, false>(blockIdx.x, A, Wt + 2 * 16384, foldB + 2 * 2048, hs,
                          es, nullptr, NN, sW, sF, sC);
}

// ---------- gather: inline alpha + weighted sum + bias + LN + ReLU ----------
// 16 lanes per dst node; lane j owns channels 8j..8j+7; head h=j>>2; 4 nodes
// per wave. w = exp(lrelu(es[src][h] + ed[dst][h] + eaw[eid][h])) computed
// IN-REGISTER (no wbuf scatter/read). 2-edge unroll, dual accumulator banks.
__device__ __forceinline__ void fma8(float* a, float w, int4 p) {
  const unsigned m = 0xFFFF0000u;
  a[0] += w * __uint_as_float(((unsigned)p.x) << 16);
  a[1] += w * __uint_as_float(((unsigned)p.x) & m);
  a[2] += w * __uint_as_float(((unsigned)p.y) << 16);
  a[3] += w * __uint_as_float(((unsigned)p.y) & m);
  a[4] += w * __uint_as_float(((unsigned)p.z) << 16);
  a[5] += w * __uint_as_float(((unsigned)p.z) & m);
  a[6] += w * __uint_as_float(((unsigned)p.w) << 16);
  a[7] += w * __uint_as_float(((unsigned)p.w) & m);
}

__device__ __forceinline__ float edge_w(float esv, float edv, float eav) {
  float v = esv + edv + eav;
  v = (v >= 0.f) ? v : 0.2f * v;
  return __expf(v);  // alphas O(1): safe without max-subtraction
}

__device__ __forceinline__ void gather_body16(
    int rs, int re, int j, int h, const int2* __restrict__ prs,
    const short* __restrict__ hs, const float* __restrict__ es,
    const float* __restrict__ eaw, float edv, const float* __restrict__ bias,
    const float* __restrict__ gamma, const float* __restrict__ beta,
    float* y) {
  float den0 = 0.f, den1 = 0.f;
  float a[8] = {0.f, 0.f, 0.f, 0.f, 0.f, 0.f, 0.f, 0.f};
  float b[8] = {0.f, 0.f, 0.f, 0.f, 0.f, 0.f, 0.f, 0.f};
  int k = rs;
  for (; k + 1 < re; k += 2) {
    int2 pr0 = prs[k];
    int2 pr1 = prs[k + 1];
    float w0 = edge_w(es[(long)pr0.x * 4 + h], edv, eaw[(long)pr0.y * 4 + h]);
    float w1 = edge_w(es[(long)pr1.x * 4 + h], edv, eaw[(long)pr1.y * 4 + h]);
    int4 p0 = *(const int4*)(hs + (long)pr0.x * 128 + j * 8);
    int4 p1 = *(const int4*)(hs + (long)pr1.x * 128 + j * 8);
    den0 += w0;
    den1 += w1;
    fma8(a, w0, p0);
    fma8(b, w1, p1);
  }
  if (k < re) {
    int2 pr0 = prs[k];
    float w0 = edge_w(es[(long)pr0.x * 4 + h], edv, eaw[(long)pr0.y * 4 + h]);
    int4 p0 = *(const int4*)(hs + (long)pr0.x * 128 + j * 8);
    den0 += w0;
    fma8(a, w0, p0);
  }
  float inv = 1.f / (den0 + den1 + 1e-16f);
  float4 b4a = ((const float4*)bias)[j * 2];
  float4 b4b = ((const float4*)bias)[j * 2 + 1];
  float o[8];
  o[0] = (a[0] + b[0]) * inv + b4a.x;
  o[1] = (a[1] + b[1]) * inv + b4a.y;
  o[2] = (a[2] + b[2]) * inv + b4a.z;
  o[3] = (a[3] + b[3]) * inv + b4a.w;
  o[4] = (a[4] + b[4]) * inv + b4b.x;
  o[5] = (a[5] + b[5]) * inv + b4b.y;
  o[6] = (a[6] + b[6]) * inv + b4b.z;
  o[7] = (a[7] + b[7]) * inv + b4b.w;
  float s1 = 0.f, s2 = 0.f;
#pragma unroll
  for (int i = 0; i < 8; ++i) {
    s1 += o[i];
    s2 += o[i] * o[i];
  }
#pragma unroll
  for (int mm = 1; mm <= 8; mm <<= 1) {
    s1 += __shfl_xor(s1, mm);
    s2 += __shfl_xor(s2, mm);
  }
  float mu = s1 * (1.f / 128.f);
  float var = s2 * (1.f / 128.f) - mu * mu;
  float rstd = rsqrtf(var + 1e-5f);
  float4 g4a = ((const float4*)gamma)[j * 2];
  float4 g4b = ((const float4*)gamma)[j * 2 + 1];
  float4 e4a = ((const float4*)beta)[j * 2];
  float4 e4b = ((const float4*)beta)[j * 2 + 1];
  y[0] = fmaxf((o[0] - mu) * rstd * g4a.x + e4a.x, 0.f);
  y[1] = fmaxf((o[1] - mu) * rstd * g4a.y + e4a.y, 0.f);
  y[2] = fmaxf((o[2] - mu) * rstd * g4a.z + e4a.z, 0.f);
  y[3] = fmaxf((o[3] - mu) * rstd * g4a.w + e4a.w, 0.f);
  y[4] = fmaxf((o[4] - mu) * rstd * g4b.x + e4b.x, 0.f);
  y[5] = fmaxf((o[5] - mu) * rstd * g4b.y + e4b.y, 0.f);
  y[6] = fmaxf((o[6] - mu) * rstd * g4b.z + e4b.z, 0.f);
  y[7] = fmaxf((o[7] - mu) * rstd * g4b.w + e4b.w, 0.f);
}

// layer-0 both convs: g<NN item (conv0: es=esU,eaw0,edC0) -> bufXI;
// g>=NN user (conv1: es=esI,eaw1,edC1) -> bufXU + edL1 fuse
__global__ __launch_bounds__(256) void gather01_k(
    const int* __restrict__ offs2, const int2* __restrict__ prs,
    const short* __restrict__ hsU, const short* __restrict__ hsI,
    const float* __restrict__ esU, const float* __restrict__ esI,
    const float* __restrict__ edC0, const float* __restrict__ edC1,
    const float* __restrict__ eaw0, const float* __restrict__ eaw1,
    const float* __restrict__ bias, const float* __restrict__ ln_g,
    const float* __restrict__ ln_b, short* __restrict__ bufXI,
    short* __restrict__ bufXU, const float* __restrict__ WdaL1,
    float* __restrict__ edL1) {
  int t = threadIdx.x;
  int j = t & 15, h = j >> 2;
  int g = blockIdx.x * 16 + (t >> 4);
  if (g >= 2 * NN) return;
  bool item = g < NN;  // NN % 16 == 0 -> uniform per block
  const short* hs = item ? hsU : hsI;
  const float* es = item ? esU : esI;
  const float* eaw = item ? eaw0 : eaw1;
  const float* bi = bias + (item ? 0 : 128);
  const float* ga = ln_g + (item ? 128 : 0);
  const float* be = ln_b + (item ? 128 : 0);
  long n = item ? g : g - NN;
  float edv = (item ? edC0 : edC1)[n * 4 + h];
  float y[8];
  gather_body16(offs2[g], offs2[g + 1], j, h, prs, hs, es, eaw, edv, bi, ga,
                be, y);
  int4 pk;
  pk.x = (int)((unsigned)(unsigned short)f2b(y[0]) |
               ((unsigned)(unsigned short)f2b(y[1]) << 16));
  pk.y = (int)((unsigned)(unsigned short)f2b(y[2]) |
               ((unsigned)(unsigned short)f2b(y[3]) << 16));
  pk.z = (int)((unsigned)(unsigned short)f2b(y[4]) |
               ((unsigned)(unsigned short)f2b(y[5]) << 16));
  pk.w = (int)((unsigned)(unsigned short)f2b(y[6]) |
               ((unsigned)(unsigned short)f2b(y[7]) << 16));
  *(int4*)((item ? bufXI : bufXU) + n * 128 + j * 8) = pk;
  if (!item) {  // fold next layer's ed = y @ WdaL1
    float e0 = 0.f, e1 = 0.f, e2 = 0.f, e3 = 0.f;
#pragma unroll
    for (int r = 0; r < 8; ++r) {
      float4 wr = ((const float4*)WdaL1)[j * 8 + r];
      e0 += y[r] * wr.x;
      e1 += y[r] * wr.y;
      e2 += y[r] * wr.z;
      e3 += y[r] * wr.w;
    }
#pragma unroll
    for (int mm = 1; mm <= 8; mm <<= 1) {
      e0 += __shfl_xor(e0, mm);
      e1 += __shfl_xor(e1, mm);
      e2 += __shfl_xor(e2, mm);
      e3 += __shfl_xor(e3, mm);
    }
    if (j == 0) ((float4*)edL1)[n] = make_float4(e0, e1, e2, e3);
  }
}

__global__ __launch_bounds__(256) void gather2_k(
    const int* __restrict__ offs, const int2* __restrict__ prs,
    const short* __restrict__ hs2, const float* __restrict__ es2,
    const float* __restrict__ edL1, const float* __restrict__ eaw2,
    const float* __restrict__ bias, const float* __restrict__ ln_g,
    const float* __restrict__ ln_b, float* __restrict__ out) {
  int t = threadIdx.x;
  int j = t & 15, h = j >> 2;
  int n = blockIdx.x * 16 + (t >> 4);
  if (n >= NN) return;
  float edv = edL1[(long)n * 4 + h];
  float y[8];
  gather_body16(offs[n], offs[n + 1], j, h, prs, hs2, es2, eaw2, edv, bias,
                ln_g, ln_b, y);
  ((float4*)out)[(long)n * 32 + j * 2] = make_float4(y[0], y[1], y[2], y[3]);
  ((float4*)out)[(long)n * 32 + j * 2 + 1] =
      make_float4(y[4], y[5], y[6], y[7]);
}

extern "C" void kernel_launch(void* const* d_in, const int* in_sizes, int n_in,
                              void* d_out, int out_size, void* d_ws,
                              size_t ws_size, hipStream_t stream) {
  const float* x_user = (const float*)d_in[0];
  const float* x_item = (const float*)d_in[1];
  const int* ei_u2i = (const int*)d_in[2];
  const int* ei_i2u = (const int*)d_in[3];
  const float* ea_u2i = (const float*)d_in[4];
  const float* ea_i2u = (const float*)d_in[5];
  const float* W_src = (const float*)d_in[6];
  const float* W_dst = (const float*)d_in[7];
  const float* W_edge = (const float*)d_in[8];
  const float* att_src = (const float*)d_in[9];
  const float* att_dst = (const float*)d_in[10];
  const float* att_edge = (const float*)d_in[11];
  const float* bias = (const float*)d_in[12];
  const float* ln_g = (const float*)d_in[13];
  const float* ln_b = (const float*)d_in[14];

  char* w = (char*)d_ws;
  auto alloc = [&](size_t bytes) {
    void* p = w;
    w += (bytes + 255) & ~(size_t)255;
    return p;
  };
  const size_t NBH = (size_t)NN * 128 * sizeof(short);
  short* hsU = (short*)alloc(NBH);
  short* hsI = (short*)alloc(NBH);
  short* hs2 = (short*)alloc(NBH);
  short* bufXI = (short*)alloc(NBH);
  short* bufXU = (short*)alloc(NBH);
  float* esU = (float*)alloc((size_t)NN * 4 * sizeof(float));
  float* esI = (float*)alloc((size_t)NN * 4 * sizeof(float));
  float* es2 = (float*)alloc((size_t)NN * 4 * sizeof(float));
  float* edC0 = (float*)alloc((size_t)NN * 4 * sizeof(float));
  float* edC1 = (float*)alloc((size_t)NN * 4 * sizeof(float));
  float* edL1 = (float*)alloc((size_t)NN * 4 * sizeof(float));
  float4* eaw0 = (float4*)alloc((size_t)EE * sizeof(float4));  // 8MB
  float4* eaw1 = (float4*)alloc((size_t)EE * sizeof(float4));  // 8MB
  float4* eaw2 = (float4*)alloc((size_t)EE * sizeof(float4));  // 8MB
  int2* prs = (int2*)alloc((size_t)2 * EE * sizeof(int2));     // 8MB
  short* Wt = (short*)alloc(3 * 16384 * sizeof(short));
  short* foldB = (short*)alloc(3 * 2048 * sizeof(short));
  float* Wea = (float*)alloc(3 * 64 * sizeof(float));
  float* WdaL1 = (float*)alloc(128 * 4 * sizeof(float));
  int* deg2 = (int*)alloc((size_t)2 * NN * sizeof(int));
  int* bsums = (int*)alloc(1024);
  int* offs2 = (int*)alloc((size_t)(2 * NN + 8) * sizeof(int));
  int* rank2 = (int*)alloc((size_t)2 * EE * sizeof(int));

  const int E2G = (2 * EE + 255) / 256;            // 3907
  const int SCAN_G2 = (2 * NN + 1023) / 1024;      // 196

  // ---- CSR (both edge types, concatenated) : 6 launches ----
  zero_f4<<<(2 * NN / 4 + 255) / 256, 256, 0, stream>>>((float4*)deg2,
                                                        2 * NN / 4);
  hist2_k<<<E2G, 256, 0, stream>>>(ei_u2i, ei_i2u, deg2, rank2);
  scan1_k<<<SCAN_G2, 256, 0, stream>>>(deg2, offs2, bsums, 2 * NN);
  scan2_k<<<1, 256, 0, stream>>>(bsums, SCAN_G2, offs2 + 2 * NN);
  scan3_k<<<SCAN_G2, 256, 0, stream>>>(offs2, bsums, 2 * NN);
  scatter_k<<<E2G, 256, 0, stream>>>(ei_u2i, ei_i2u, rank2, offs2, prs);

  // ---- params + eaw + layer 0 : 4 launches ----
  prep_k<<<195, 256, 0, stream>>>(W_src, W_dst, W_edge, att_src, att_dst,
                                  att_edge, Wt, foldB, Wea, WdaL1);
  eaw_k<<<2 * EAW_G, 256, 0, stream>>>(ea_u2i, ea_i2u, Wea, eaw0, eaw1, eaw2);
  gemm01_k<<<2 * GEMM_NG, 256, 0, stream>>>(x_user, x_item, Wt, foldB, hsU,
                                            hsI, esU, esI, edC0, edC1);
  gather01_k<<<2 * NN / 16, 256, 0, stream>>>(
      offs2, prs, hsU, hsI, esU, esI, edC0, edC1, (const float*)eaw0,
      (const float*)eaw1, bias, ln_g, ln_b, bufXI, bufXU, WdaL1, edL1);

  // ---- layer 1 (user path only; item path dead) : 2 launches ----
  gemm2_k<<<GEMM_NG, 256, 0, stream>>>(bufXI, Wt, foldB, hs2, es2);
  gather2_k<<<NN / 16, 256, 0, stream>>>(offs2 + NN, prs, hs2, es2, edL1,
                                         (const float*)eaw2, bias + 3 * 128,
                                         ln_g + 2 * 128, ln_b + 2 * 128,
                                         (float*)d_out);
}